// Round 8
// baseline (191.806 us; speedup 1.0000x reference)
//
#include <hip/hip_runtime.h>
#include <hip/hip_bf16.h>
#include <stdint.h>

// LightNet attention fwd. B=2, T=2048, HID=1024, H=8, DK=DV=128, LR=128.
// Contract (R1-R4): inputs fp32, output fp32.
//
// o_t[v] = scale * sum_k (q_t[k]/E_t[k]) * sum_{s<=t} e_s[k] v_s[v],
// e=exp(k), E=cumsum(e). Chunked Tc=128: pass1 (MFMA) Esum + Ut=(e^T V)^T;
// pass2 exclusive chunk prefix; pass3 (MFMA) intra(causal)+inter + atomic
// row sum-of-squares; norm_gate2 elementwise; final GEMM fully async.
//
// R16->R17: T1 XCD-aware block swizzle on proj_kernel (800 blocks) and
// gemm_bt64 (512 blocks): each XCD gets a contiguous chunk of the linear
// grid, so blocks sharing a weight panel co-locate on one XCD's L2 (panel
// fetched into 1 L2 instead of 8). Both grids %8==0 -> simple bijective
// swizzle. Pure index remap; math/layout bit-identical.
// All R11 conflict-free layouts preserved (conflicts == 0 verified).

typedef short short8 __attribute__((ext_vector_type(8)));
typedef float f32x4 __attribute__((ext_vector_type(4)));

#define T_SEQ 2048
#define HIDN  1024
#define SCALE 0.08838834764831845f   // 128^-0.5
#define LDSP  136                    // padded LDS row stride (shorts)

// ---------------- bf16 bit helpers ----------------
__device__ __forceinline__ float blo(unsigned int u){
  union{unsigned int i; float f;} v; v.i = u << 16; return v.f;
}
__device__ __forceinline__ float bhi(unsigned int u){
  union{unsigned int i; float f;} v; v.i = u & 0xffff0000u; return v.f;
}
__device__ __forceinline__ float bu2f(unsigned short u){
  union{unsigned int i; float f;} v; v.i = ((unsigned int)u) << 16; return v.f;
}
__device__ __forceinline__ unsigned short f2bu(float f){
  union{float f; unsigned int i;} v; v.f = f;
  unsigned int x = v.i;
  x += 0x7fffu + ((x >> 16) & 1u);     // RNE
  return (unsigned short)(x >> 16);
}
__device__ __forceinline__ void async16(const void* g, void* l){
  __builtin_amdgcn_global_load_lds(
      (const __attribute__((address_space(1))) unsigned int*)g,
      (__attribute__((address_space(3))) unsigned int*)l, 16, 0, 0);
}

// ---------------- fused input cast + SumSq zeroing ------------------------
__global__ __launch_bounds__(256) void convert_all(
    const float* __restrict__ X,  const float* __restrict__ Wq,
    const float* __restrict__ Wk, const float* __restrict__ Wv,
    const float* __restrict__ Wg1,const float* __restrict__ Wg2,
    const float* __restrict__ gnw,const float* __restrict__ Wo,
    unsigned short* __restrict__ base, float* __restrict__ SumSq)
{
  int q = blockIdx.x * 256 + threadIdx.x;
  const float* src; unsigned short* dst; int rel = q;
  if (rel < 1048576)            { src = X;   dst = base;            }
  else if ((rel -= 1048576) < 262144) { src = Wq;  dst = base + 4194304; }
  else if ((rel -=  262144) < 262144) { src = Wk;  dst = base + 5242880; }
  else if ((rel -=  262144) < 262144) { src = Wv;  dst = base + 6291456; }
  else if ((rel -=  262144) < 262144) { src = Wo;  dst = base + 7340032; }
  else if ((rel -=  262144) <  32768) { src = Wg1; dst = base + 8388608; }
  else if ((rel -=   32768) <  32768) { src = Wg2; dst = base + 8519680; }
  else if ((rel -=   32768) <    256) { src = gnw; dst = base + 8650752; }
  else { rel -= 256;                              // zero SumSq (4096 floats)
    ((float4*)SumSq)[rel] = make_float4(0.f,0.f,0.f,0.f); return; }
  float4 v = ((const float4*)src)[rel];
  ushort4 o; o.x=f2bu(v.x); o.y=f2bu(v.y); o.z=f2bu(v.z); o.w=f2bu(v.w);
  ((ushort4*)dst)[rel] = o;
}

// ---------------- MFMA GEMM core: C(128x128)=A@B^T, BK=64 ----------------
// LDS tile [128 rows][8 chunks of 16B]; chunk cl of row r holds source
// chunk cl^(r&7) (involution; applied on the global source address so the
// global_load_lds destination stays linear). Frag reads use the same XOR:
// lanes 0-7 hit 8 distinct quad-bank groups -> conflict-free.
__device__ __forceinline__ void gemm_core(
    const unsigned short* __restrict__ A, const unsigned short* __restrict__ B,
    int K, int row0, int col0,
    unsigned short* sA, unsigned short* sB, f32x4 acc[4][4], int tid)
{
  const int lane = tid & 63;
  const int wm = (tid >> 6) & 1, wn = tid >> 7;
  const int wb = tid & 192;                // wave-uniform chunk base
  for (int k0 = 0; k0 < K; k0 += 64){
    __syncthreads();                       // prev iter's LDS reads done
#pragma unroll
    for (int r = 0; r < 4; ++r){
      int idx  = r*256 + tid;              // 1024 chunks of 16B per tile
      int mrow = idx >> 3;                 // row 0..127
      int kc   = ((idx & 7) ^ (mrow & 7)) * 8;   // pre-swizzled source col
      async16(A + (size_t)(row0 + mrow)*K + k0 + kc,
              sA + (size_t)(r*256 + wb)*8);
      async16(B + (size_t)(col0 + mrow)*K + k0 + kc,
              sB + (size_t)(r*256 + wb)*8);
    }
    __syncthreads();                       // drains vmcnt before barrier
#pragma unroll
    for (int h = 0; h < 2; ++h){
      short8 av[4], bv[4];
#pragma unroll
      for (int i=0;i<4;i++){
        int ra = wm*64 + i*16 + (lane&15);
        av[i] = *(const short8*)(sA + (size_t)ra*64
                                 + (((h*4 + (lane>>4)) ^ (ra & 7)) * 8));
      }
#pragma unroll
      for (int j=0;j<4;j++){
        int rb = wn*64 + j*16 + (lane&15);
        bv[j] = *(const short8*)(sB + (size_t)rb*64
                                 + (((h*4 + (lane>>4)) ^ (rb & 7)) * 8));
      }
#pragma unroll
      for (int i=0;i<4;i++)
#pragma unroll
        for (int j=0;j<4;j++)
          acc[i][j] = __builtin_amdgcn_mfma_f32_16x16x32_bf16(av[i], bv[j], acc[i][j], 0, 0, 0);
    }
  }
}

// bf16 epilogue via LDS. act: 0 none, 1 silu/swish, 2 exp.
__device__ __forceinline__ void epilogue_lds(
    f32x4 acc[4][4], int row0, int col0, int tid, int ldc, int act,
    unsigned short* __restrict__ Cb, unsigned short* sC)
{
  const int lane = tid & 63;
  const int wm = (tid >> 6) & 1, wn = tid >> 7;
#pragma unroll
  for (int p=0;p<4;p++){
    __syncthreads();
    if (wm == (p>>1)){
#pragma unroll
      for (int ii=0; ii<2; ii++){
        int i = (p&1)*2 + ii;
        int lr = i*16 + ((lane>>4)<<2) - (p&1)*32;   // local row in [0,32)
#pragma unroll
        for (int j=0;j<4;j++){
          int col = wn*64 + j*16 + (lane&15);
#pragma unroll
          for (int r=0;r<4;r++){
            float v = acc[i][j][r];
            if (act == 1) v = v / (1.f + __expf(-v));
            else if (act == 2) v = __expf(v);
            sC[(lr+r)*128 + col] = f2bu(v);
          }
        }
      }
    }
    __syncthreads();
#pragma unroll
    for (int c = tid; c < 512; c += 256){  // 32 rows x 256B
      int rr = c >> 4, off = (c & 15)*8;
      *(uint4*)&Cb[(size_t)(row0 + p*32 + rr)*ldc + col0 + off] =
          *(const uint4*)&sC[rr*128 + off];
    }
  }
}

// fp32 direct epilogue (64B full-line segments).
__device__ __forceinline__ void epilogue_f32(
    f32x4 acc[4][4], int row0, int col0, int tid, int ldc,
    float* __restrict__ Cf)
{
  const int lane = tid & 63;
  const int wm = (tid >> 6) & 1, wn = tid >> 7;
#pragma unroll
  for (int i=0;i<4;i++){
    int rbase = row0 + wm*64 + i*16 + ((lane>>4)<<2);
#pragma unroll
    for (int j=0;j<4;j++){
      int col = col0 + wn*64 + j*16 + (lane&15);
#pragma unroll
      for (int r=0;r<4;r++)
        Cf[(size_t)(rbase + r)*ldc + col] = acc[i][j][r];
    }
  }
}

// V^T epilogue: direct ushort4 stores, VT[(b*8+h)*128 + v][t:2048].
__device__ __forceinline__ void epilogue_vt(
    f32x4 acc[4][4], int row0, int col0, int tid,
    unsigned short* __restrict__ VT)
{
  const int lane = tid & 63, quad = lane >> 4, l15 = lane & 15;
  const int wm = (tid >> 6) & 1, wn = tid >> 7;
  size_t vtbase = ((size_t)(row0 >> 11)*8 + (col0 >> 7))*128;
  int trow0 = row0 & 2047;
#pragma unroll
  for (int i=0;i<4;i++){
    int t = trow0 + wm*64 + i*16 + quad*4;
#pragma unroll
    for (int j=0;j<4;j++){
      int v = wn*64 + j*16 + l15;
      ushort4 o;
      o.x = f2bu(acc[i][j][0]); o.y = f2bu(acc[i][j][1]);
      o.z = f2bu(acc[i][j][2]); o.w = f2bu(acc[i][j][3]);
      *(ushort4*)&VT[(vtbase + v)*2048 + t] = o;
    }
  }
}

// Fused QKV+G1 projection. 800 blocks, XCD-swizzled (chunks of 100/XCD):
// decoded (bx,by): by<8 Q(silu), <16 K->e (exp), <24 V->V^T, ==24 G1.
__global__ __launch_bounds__(256, 4) void proj_kernel(
    const unsigned short* __restrict__ X,
    const unsigned short* __restrict__ Wq, const unsigned short* __restrict__ Wk,
    const unsigned short* __restrict__ Wv, const unsigned short* __restrict__ Wg1,
    unsigned short* __restrict__ Qb, unsigned short* __restrict__ Eb,
    unsigned short* __restrict__ VT, unsigned short* __restrict__ G1b)
{
  __shared__ unsigned short sA[128*64], sB[128*64];
  int tid = threadIdx.x;
  // T1 XCD swizzle: lin -> (lin&7)*100 + lin/8 (bijective, 800%8==0).
  int lin = blockIdx.y * 32 + blockIdx.x;
  int swz = (lin & 7) * 100 + (lin >> 3);
  int bx = swz & 31, by = swz >> 5;
  int which = by >> 3;
  const unsigned short* Bp = (which==0)?Wq:(which==1)?Wk:(which==2)?Wv:Wg1;
  int row0 = bx * 128;
  int col0 = (which==3) ? 0 : (by & 7) * 128;
  f32x4 acc[4][4] = {};
  gemm_core(X, Bp, HIDN, row0, col0, sA, sB, acc, tid);
  if      (which==0) epilogue_lds(acc,row0,col0,tid,HIDN,1,Qb, sA);
  else if (which==1) epilogue_lds(acc,row0,col0,tid,HIDN,2,Eb, sA);  // e=exp(k)
  else if (which==2) epilogue_vt (acc,row0,col0,tid,VT);
  else               epilogue_lds(acc,row0,col0,tid,128 ,0,G1b,sA);
}

// ---------------- 128x64-tile GEMM (2x blocks -> 2 blocks/CU) ------------
__device__ __forceinline__ void gemm_core64(
    const unsigned short* __restrict__ A, const unsigned short* __restrict__ B,
    int K, int row0, int col0,
    unsigned short* sA, unsigned short* sB, f32x4 acc[4][2], int tid)
{
  const int lane = tid & 63, quad = lane >> 4, l15 = lane & 15;
  const int wm = (tid >> 6) & 1, wn = tid >> 7;
  const int wb = tid & 192;
  for (int k0 = 0; k0 < K; k0 += 64){
    __syncthreads();
#pragma unroll
    for (int r = 0; r < 4; ++r){
      int idx  = r*256 + tid;
      int mrow = idx >> 3;
      int kc   = ((idx & 7) ^ (mrow & 7)) * 8;
      async16(A + (size_t)(row0 + mrow)*K + k0 + kc,
              sA + (size_t)(r*256 + wb)*8);
    }
#pragma unroll
    for (int r = 0; r < 2; ++r){
      int idx  = r*256 + tid;
      int brow = idx >> 3;                 // 0..63
      int kc   = ((idx & 7) ^ (brow & 7)) * 8;
      async16(B + (size_t)(col0 + brow)*K + k0 + kc,
              sB + (size_t)(r*256 + wb)*8);
    }
    __syncthreads();
#pragma unroll
    for (int h = 0; h < 2; ++h){
      short8 av[4], bv[2];
#pragma unroll
      for (int i=0;i<4;i++){
        int ra = wm*64 + i*16 + l15;
        av[i] = *(const short8*)(sA + (size_t)ra*64
                                 + (((h*4 + quad) ^ (ra & 7)) * 8));
      }
#pragma unroll
      for (int j=0;j<2;j++){
        int rb = wn*32 + j*16 + l15;
        bv[j] = *(const short8*)(sB + (size_t)rb*64
                                 + (((h*4 + quad) ^ (rb & 7)) * 8));
      }
#pragma unroll
      for (int i=0;i<4;i++)
#pragma unroll
        for (int j=0;j<2;j++)
          acc[i][j] = __builtin_amdgcn_mfma_f32_16x16x32_bf16(av[i], bv[j], acc[i][j], 0, 0, 0);
    }
  }
}

__global__ __launch_bounds__(256, 4) void gemm_bt64(
    const unsigned short* __restrict__ A, const unsigned short* __restrict__ B,
    int K, int ldc, int act, float* __restrict__ Cf,
    unsigned short* __restrict__ Cb)
{
  __shared__ unsigned short sA[128*64], sB[64*64];
  int tid = threadIdx.x;
  const int lane = tid & 63, quad = lane >> 4, l15 = lane & 15;
  const int wm = (tid >> 6) & 1, wn = tid >> 7;
  // T1 XCD swizzle (512 blocks -> chunks of 64/XCD; bijective, 512%8==0).
  int lin = blockIdx.y * 32 + blockIdx.x;
  int swz = (lin & 7) * 64 + (lin >> 3);
  int row0 = (swz & 31) * 128, col0 = (swz >> 5) * 64;
  f32x4 acc[4][2] = {};
  gemm_core64(A, B, K, row0, col0, sA, sB, acc, tid);
  if (Cb){
    unsigned short* sC = sA;               // 32 x 64 staging
#pragma unroll
    for (int p=0;p<4;p++){
      __syncthreads();
      if (wm == (p>>1)){
#pragma unroll
        for (int ii=0; ii<2; ii++){
          int i = (p&1)*2 + ii;
          int lr = i*16 + quad*4 - (p&1)*32;
#pragma unroll
          for (int j=0;j<2;j++){
            int col = wn*32 + j*16 + l15;
#pragma unroll
            for (int r=0;r<4;r++){
              float v = acc[i][j][r];
              if (act == 1) v = v / (1.f + __expf(-v));
              else if (act == 2) v = __expf(v);
              sC[(lr+r)*64 + col] = f2bu(v);
            }
          }
        }
      }
      __syncthreads();
      {
        int rr = tid >> 3, off = (tid & 7)*8;   // 32 rows x 128B
        *(uint4*)&Cb[(size_t)(row0 + p*32 + rr)*ldc + col0 + off] =
            *(const uint4*)&sC[rr*64 + off];
      }
    }
  } else {
#pragma unroll
    for (int i=0;i<4;i++){
      int rbase = row0 + wm*64 + i*16 + quad*4;
#pragma unroll
      for (int j=0;j<2;j++){
        int col = col0 + wn*32 + j*16 + l15;
#pragma unroll
        for (int r=0;r<4;r++)
          Cf[(size_t)(rbase + r)*ldc + col] = acc[i][j][r];
      }
    }
  }
}

// ---------------- pass 1 (MFMA): Esum[k], Ut[v][k] = sum_s V[s][v] e[s][k]
// k-SPLIT: grid 512 = (bh:4 | ch:4 | kh:1), 512 thr = 8 waves, ~51 KB LDS
// -> 2 independent blocks/CU. Each block: full V^T (async16, XOR-chunked),
// its own 64-col e-half transpose, Esum half, U k-half. No duplicated math.
__global__ __launch_bounds__(512, 4) void attn_pass1(
    const unsigned short* __restrict__ Eb, const unsigned short* __restrict__ VT,
    unsigned short* __restrict__ U, float* __restrict__ Esum)
{
  __shared__ unsigned short Vt[128*128];    // 32 KB, linear, XOR-chunked
  __shared__ unsigned short Et[64*LDSP];    // 17 KB (transposed e half)
  __shared__ float seg_part[8*64];
  int tid = threadIdx.x;
  const int lane = tid & 63, quad = lane >> 4, l15 = lane & 15;
  const int w = tid >> 6;                  // wave 0..7
  const int Rb = (w & 3)*32;               // v rows (2 i-tiles)
  const int Cbk = (w >> 2)*32;             // local k cols (2 j-tiles)
  int bx = blockIdx.x;
  int bh = bx >> 5, ch = (bx >> 1) & 15, kh = bx & 1;
  int b = bh >> 3, h = bh & 7;
  size_t rowbase = (size_t)(b*T_SEQ + ch*128)*HIDN + h*128 + kh*64;
  const unsigned short* VTb = VT + (size_t)bh*128*2048 + ch*128;

  // ---- stage V^T [v 128][s 128] via async16; source chunk-XOR swizzled ----
#pragma unroll
  for (int it=0; it<4; ++it){
    int slot = it*512 + tid;
    int vrow = slot >> 4, c = slot & 15;
    int cs = (c & 8) | ((c & 7) ^ (vrow & 7));
    async16(VTb + (size_t)vrow*2048 + cs*8,
            Vt + (size_t)(it*512 + (tid & 448))*8);
  }
  // ---- transpose-stage e half (rotated scalar stores) ----
#pragma unroll
  for (int i=0;i<2;i++){
    int u = tid + i*512; int t = u >> 3, kc = (u & 7)*8;
    int trot = (t + kc) & 127;
    unsigned short tmp[8];
    *(uint4*)tmp = *(const uint4*)&Eb[rowbase + (size_t)t*HIDN + kc];
#pragma unroll
    for (int j=0;j<8;j++) Et[(kc+j)*LDSP + trot] = tmp[j];
  }
  __syncthreads();

  { // Esum half: 64 k-rows, 8 segments of 16 t-cols
    int seg = tid >> 6, k = tid & 63;
    float s = 0.f;
    for (int c = seg*16; c < seg*16+16; ++c)
      s += bu2f(Et[k*LDSP + ((c + (k & 120)) & 127)]);
    seg_part[seg*64 + k] = s;
  }
  __syncthreads();
  if (tid < 64){
    float s = 0.f;
#pragma unroll
    for (int ss=0; ss<8; ++ss) s += seg_part[ss*64 + tid];
    Esum[(size_t)(bh*16 + ch)*128 + kh*64 + tid] = s;
  }

  // Ut-half = V^T @ Et^T (contraction over s); wave = 2x2 tiles of 16x16
  f32x4 acc[2][2] = {};
#pragma unroll
  for (int s0=0; s0<128; s0+=32){
    short8 av[2], bv[2];
#pragma unroll
    for (int i=0;i<2;i++){
      int ra = Rb + i*16 + l15;
      int ck = (s0>>3) + quad;
      int cx = (ck & 8) | ((ck & 7) ^ (ra & 7));
      av[i] = *(const short8*)(Vt + (size_t)ra*128 + cx*8);
    }
#pragma unroll
    for (int j=0;j<2;j++){
      int rb = Cbk + j*16 + l15;
      bv[j] = *(const short8*)(Et + rb*LDSP + ((s0 + quad*8 + (rb & 120)) & 127));
    }
#pragma unroll
    for (int i=0;i<2;i++)
#pragma unroll
      for (int j=0;j<2;j++)
        acc[i][j] = __builtin_amdgcn_mfma_f32_16x16x32_bf16(av[i], bv[j], acc[i][j], 0,0,0);
  }
  __syncthreads();                         // all Vt/Et reads done

  // stage C (bf16) into Vt region [v][64], coalesced copy-out
#pragma unroll
  for (int i=0;i<2;i++)
#pragma unroll
    for (int j=0;j<2;j++){
      int k = Cbk + j*16 + l15;
#pragma unroll
      for (int r=0;r<4;r++){
        int v = Rb + i*16 + quad*4 + r;
        Vt[v*64 + k] = f2bu(acc[i][j][r]);
      }
    }
  __syncthreads();
  unsigned short* Ub = U + (size_t)(bh*16 + ch)*16384;
#pragma unroll
  for (int i=0;i<2;i++){
    int u = tid + i*512; int v = u >> 3, kc8 = (u & 7)*8;
    *(uint4*)&Ub[v*128 + kh*64 + kc8] = *(const uint4*)&Vt[v*64 + kc8];
  }
}

// ---------------- pass 2: exclusive prefix over chunks (in place) ----------
// Depth-4 parallel scan: thread (pos,grp) loads its 4 chunks independently,
// local prefix, LDS exchange of group sums, write back. Grid 1024 (16 bh x
// 64 slices), 256 thr = 64 positions x 4 groups.
__global__ __launch_bounds__(256) void attn_pass2(
    unsigned short* __restrict__ U, float* __restrict__ Esum)
{
  __shared__ float4 gs[4][64];
  int tid = threadIdx.x;
  int bh = blockIdx.x >> 6, slice = blockIdx.x & 63;
  int pos = tid & 63, grp = tid >> 6;
  size_t P4 = ((size_t)slice*64 + pos)*4;          // short offset in plane
  ushort4 tv[4];
#pragma unroll
  for (int c=0;c<4;c++)                            // 4 INDEPENDENT loads
    tv[c] = *(const ushort4*)&U[(size_t)(bh*16 + grp*4 + c)*16384 + P4];
  float4 run = make_float4(0.f,0.f,0.f,0.f);
  float4 excl[4];
#pragma unroll
  for (int c=0;c<4;c++){
    excl[c] = run;
    run.x += bu2f(tv[c].x); run.y += bu2f(tv[c].y);
    run.z += bu2f(tv[c].z); run.w += bu2f(tv[c].w);
  }
  gs[grp][pos] = run;
  __syncthreads();
  float4 base = make_float4(0.f,0.f,0.f,0.f);
  for (int g=0; g<grp; ++g){
    float4 t = gs[g][pos];
    base.x += t.x; base.y += t.y; base.z += t.z; base.w += t.w;
  }
#pragma unroll
  for (int c=0;c<4;c++){
    ushort4 w4;
    w4.x = f2bu(base.x + excl[c].x); w4.y = f2bu(base.y + excl[c].y);
    w4.z = f2bu(base.z + excl[c].z); w4.w = f2bu(base.w + excl[c].w);
    *(ushort4*)&U[(size_t)(bh*16 + grp*4 + c)*16384 + P4] = w4;
  }
  if (slice < 2 && tid < 64){                      // Esum prefix (exact serial)
    int k = slice*64 + tid;
    float r = 0.f;
    for (int c=0;c<16;c++){
      float* q = &Esum[(size_t)(bh*16 + c)*128 + k];
      float t = *q; *q = r; r += t;
    }
  }
}

// ---------------- pass 3 (MFMA): o = qn@Cprev + causal(qn@e^T)@V + SumSq --
// 1024 threads = 16 waves, 2 blocks/CU (VGPR must stay <=64!).
// Ut read DIRECT from global (L2-resident, coalesced-per-row frags).
// bufA: Q->qn->P->Ostage ; bufB: e, then V^T (async16 overlay).
__global__ __launch_bounds__(1024, 2) void attn_pass3(
    const unsigned short* __restrict__ Eb, const unsigned short* __restrict__ Qb,
    const unsigned short* __restrict__ VT, const unsigned short* __restrict__ U,
    const float* __restrict__ Esum, unsigned short* __restrict__ Oatt,
    float* __restrict__ SumSq)
{
  __shared__ unsigned short bufA[128*LDSP];       // 34.8 KB
  __shared__ unsigned short bufB[128*LDSP];       // 34.8 KB (e, then V^T)
  __shared__ float seg_part[8*128];

  int tid = threadIdx.x;
  const int lane = tid & 63, quad = lane >> 4, l15 = lane & 15;
  const int w = tid >> 6;                  // wave 0..15
  const int Rb = (w & 3)*32;               // t rows (2 i-tiles)
  const int Cbn = (w >> 2)*32;             // s / v cols (2 j-tiles)
  int bh = blockIdx.x >> 4, ch = blockIdx.x & 15;
  int b = bh >> 3, h = bh & 7;
  size_t rowbase = (size_t)(b*T_SEQ + ch*128)*HIDN + h*128;
  const unsigned short* Ublk = U + (size_t)blockIdx.x*16384;
  const unsigned short* VTb = VT + (size_t)bh*128*2048 + ch*128;

  // ---- stage Q, e ----
#pragma unroll
  for (int i=0;i<2;i++){
    int u = tid + i*1024; int t = u >> 4, kc = (u & 15)*8;
    *(uint4*)&bufA[t*LDSP + kc] = *(const uint4*)&Qb[rowbase + (size_t)t*HIDN + kc];
    *(uint4*)&bufB[t*LDSP + kc] = *(const uint4*)&Eb[rowbase + (size_t)t*HIDN + kc];
  }
  __syncthreads();

  // ---- qn = q*SCALE/E_t ; 8-way segmented inclusive cumsum over t ----
  {
    int col = tid & 127, seg = tid >> 7;
    float psum = 0.f;
    for (int s = seg*16; s < seg*16+16; ++s) psum += bu2f(bufB[s*LDSP + col]);
    seg_part[seg*128 + col] = psum;
    __syncthreads();
    float run = Esum[(size_t)blockIdx.x*128 + col];
    for (int ss=0; ss<8; ++ss) if (ss < seg) run += seg_part[ss*128 + col];
    for (int s = seg*16; s < seg*16+16; ++s){
      run += bu2f(bufB[s*LDSP + col]);
      float q = bu2f(bufA[s*LDSP + col]);
      bufA[s*LDSP + col] = f2bu(q * SCALE * __builtin_amdgcn_rcpf(run));
    }
  }
  __syncthreads();

  // ---- inter: O = QN @ Ut^T (Ut direct from global) ; scores: P = QN@E^T --
  f32x4 accO[2][2] = {}, accP[2][2] = {};
#pragma unroll
  for (int k0=0; k0<128; k0+=32){
    short8 av[2], bv[2];
#pragma unroll
    for (int i=0;i<2;i++)
      av[i] = *(const short8*)(bufA + (Rb + i*16 + l15)*LDSP + k0 + quad*8);
#pragma unroll
    for (int j=0;j<2;j++)
      bv[j] = *(const short8*)(Ublk + (size_t)(Cbn + j*16 + l15)*128 + k0 + quad*8);
#pragma unroll
    for (int i=0;i<2;i++)
#pragma unroll
      for (int j=0;j<2;j++)
        accO[i][j] = __builtin_amdgcn_mfma_f32_16x16x32_bf16(av[i], bv[j], accO[i][j], 0,0,0);
#pragma unroll
    for (int j=0;j<2;j++)
      bv[j] = *(const short8*)(bufB + (Cbn + j*16 + l15)*LDSP + k0 + quad*8);
#pragma unroll
    for (int i=0;i<2;i++)
#pragma unroll
      for (int j=0;j<2;j++)
        accP[i][j] = __builtin_amdgcn_mfma_f32_16x16x32_bf16(av[i], bv[j], accP[i][j], 0,0,0);
  }
  __syncthreads();                        // all e reads done

  // ---- V^T -> bufB (async16, overlays e) ; masked P -> bufA [t][s] ----
#pragma unroll
  for (int it=0; it<2; ++it){
    int slot = it*1024 + tid;
    int vrow = slot >> 4, c = slot & 15;
    int cs = (c & 8) | ((c & 7) ^ (vrow & 7));
    async16(VTb + (size_t)vrow*2048 + cs*8,
            bufB + (size_t)(it*1024 + (tid & 960))*8);
  }
#pragma unroll
  for (int i=0;i<2;i++){
#pragma unroll
    for (int j=0;j<2;j++){
      int s = Cbn + j*16 + l15;
#pragma unroll
      for (int r=0;r<4;r++){
        int t = Rb + i*16 + quad*4 + r;
        bufA[t*LDSP + s] = f2bu(s <= t ? accP[i][j][r] : 0.f);
      }
    }
  }
  __syncthreads();                        // drains vmcnt (V^T) + lgkm (P)

  // ---- intra: O += P @ V^T (XOR-chunked bv reads) ----
#pragma unroll
  for (int k0=0; k0<128; k0+=32){
    short8 av[2], bv[2];
#pragma unroll
    for (int i=0;i<2;i++)
      av[i] = *(const short8*)(bufA + (Rb + i*16 + l15)*LDSP + k0 + quad*8);
#pragma unroll
    for (int j=0;j<2;j++){
      int rv = Cbn + j*16 + l15;
      int ck = (k0>>3) + quad;
      int cx = (ck & 8) | ((ck & 7) ^ (rv & 7));
      bv[j] = *(const short8*)(bufB + (size_t)rv*128 + cx*8);
    }
#pragma unroll
    for (int i=0;i<2;i++)
#pragma unroll
      for (int j=0;j<2;j++)
        accO[i][j] = __builtin_amdgcn_mfma_f32_16x16x32_bf16(av[i], bv[j], accO[i][j], 0,0,0);
  }
  __syncthreads();                        // all bufA (P) reads done

  // ---- O -> bufA (bf16) ----
#pragma unroll
  for (int i=0;i<2;i++){
#pragma unroll
    for (int j=0;j<2;j++){
      int vv = Cbn + j*16 + l15;
#pragma unroll
      for (int r=0;r<4;r++){
        int t = Rb + i*16 + quad*4 + r;
        bufA[t*LDSP + vv] = f2bu(accO[i][j][r]);
      }
    }
  }
  __syncthreads();

  // ---- per-row sum of squares (this head's 128 cols) ----
  {
    int seg = tid >> 7, row = tid & 127;
    float s = 0.f;
    for (int c = seg*16; c < seg*16+16; ++c){
      float x = bu2f(bufA[row*LDSP + c]); s += x*x;
    }
    seg_part[seg*128 + row] = s;
  }
  // ---- coalesced O write ----
#pragma unroll
  for (int i=0;i<2;i++){
    int u = tid + i*1024; int t = u >> 4, kc = (u & 15)*8;
    *(uint4*)&Oatt[rowbase + (size_t)t*HIDN + kc] = *(const uint4*)&bufA[t*LDSP + kc];
  }
  __syncthreads();
  if (tid < 128){
    float s = 0.f;
#pragma unroll
    for (int ss=0; ss<8; ++ss) s += seg_part[ss*128 + tid];
    atomicAdd(&SumSq[(size_t)b*T_SEQ + ch*128 + tid], s);
  }
}

// ---- norm_gate2: elementwise RMSNorm(SumSq)*gnw*swish-gate -> bf16 -------
// 2 rows/block, uint4 (8 bf16) per thread.
__global__ __launch_bounds__(256) void norm_gate2(
    const unsigned short* __restrict__ Oatt, const unsigned short* __restrict__ Gt,
    const unsigned short* __restrict__ gnw, const float* __restrict__ SumSq,
    unsigned short* __restrict__ Onorm)
{
  int tid = threadIdx.x;
  int row = blockIdx.x*2 + (tid >> 7);
  int col = (tid & 127)*8;
  float rstd = rsqrtf(SumSq[row] * (1.f/1024.f) + 1e-5f);
  uint4 o4 = *(const uint4*)&Oatt[(size_t)row*HIDN + col];
  uint4 g4 = *(const uint4*)&Gt  [(size_t)row*HIDN + col];
  uint4 w4 = *(const uint4*)&gnw[col];
  auto mul2 = [&](unsigned int o, unsigned int g, unsigned int wv)->unsigned int{
    float lo = blo(o) * rstd * blo(wv) * blo(g);
    float hi = bhi(o) * rstd * bhi(wv) * bhi(g);
    return (unsigned int)f2bu(lo) | ((unsigned int)f2bu(hi) << 16);
  };
  uint4 r4;
  r4.x = mul2(o4.x, g4.x, w4.x); r4.y = mul2(o4.y, g4.y, w4.y);
  r4.z = mul2(o4.z, g4.z, w4.z); r4.w = mul2(o4.w, g4.w, w4.w);
  *(uint4*)&Onorm[(size_t)row*HIDN + col] = r4;
}

// ---------------- launch ----------------
extern "C" void kernel_launch(void* const* d_in, const int* in_sizes, int n_in,
                              void* d_out, int out_size, void* d_ws, size_t ws_size,
                              hipStream_t stream) {
  unsigned short* wsS = (unsigned short*)d_ws;     // ~69 MiB used

  unsigned short* Xc   = wsS;              // 4,194,304
  unsigned short* Wqc  = wsS + 4194304;
  unsigned short* Wkc  = wsS + 5242880;
  unsigned short* Wvc  = wsS + 6291456;
  unsigned short* Woc  = wsS + 7340032;
  unsigned short* Wg1c = wsS + 8388608;
  unsigned short* Wg2c = wsS + 8519680;
  unsigned short* gnwc = wsS + 8650752;
  unsigned short* Qb   = wsS + 8651776;
  unsigned short* Eb   = wsS + 12846080;   // e = exp(k), bf16
  unsigned short* VTb  = wsS + 17040384;   // V^T: [(b*8+h)*128 + v][t:2048]
  unsigned short* G1b  = wsS + 21234688;
  unsigned short* Gt   = wsS + 21758976;
  unsigned short* Ub   = wsS + 25953280;
  unsigned short* Oattb= wsS + 30147584;
  float*          Esum = (float*)(wsS + 34341888);  // 32,768 floats
  float*          SumSq= (float*)(wsS + 34407424);  //  4,096 floats
  unsigned short* Onorm = Qb;              // Q dead after pass3

  convert_all<<<8453, 256, 0, stream>>>(
      (const float*)d_in[0], (const float*)d_in[1], (const float*)d_in[2],
      (const float*)d_in[3], (const float*)d_in[4], (const float*)d_in[5],
      (const float*)d_in[6], (const float*)d_in[7], wsS, SumSq);

  proj_kernel<<<dim3(32,25), 256, 0, stream>>>(Xc, Wqc, Wkc, Wvc, Wg1c, Qb, Eb, VTb, G1b);
  gemm_bt64 <<<dim3(32,16), 256, 0, stream>>>(G1b, Wg2c, 128, HIDN, 1, nullptr, Gt);
  attn_pass1<<<512, 512, 0, stream>>>(Eb, VTb, Ub, Esum);
  attn_pass2<<<1024, 256, 0, stream>>>(Ub, Esum);
  attn_pass3<<<256, 1024, 0, stream>>>(Eb, Qb, VTb, Ub, Esum, Oattb, SumSq);
  norm_gate2<<<2048, 256, 0, stream>>>(Oattb, Gt, gnwc, SumSq, Onorm);
  gemm_bt64 <<<dim3(32,16), 256, 0, stream>>>(Onorm, Woc, HIDN, 1024, 0,
                                              (float*)d_out, nullptr);
}

// Round 9
// 184.061 us; speedup vs baseline: 1.0421x; 1.0421x over previous
//
#include <hip/hip_runtime.h>
#include <hip/hip_bf16.h>
#include <stdint.h>

// LightNet attention fwd. B=2, T=2048, HID=1024, H=8, DK=DV=128, LR=128.
// Contract (R1-R4): inputs fp32, output fp32.
//
// o_t[v] = scale * sum_k (q_t[k]/E_t[k]) * sum_{s<=t} e_s[k] v_s[v],
// e=exp(k), E=cumsum(e). Chunked Tc=128: pass1 (MFMA) Esum + Ut=(e^T V)^T;
// pass2 exclusive chunk prefix; pass3 (MFMA) intra(causal)+inter + atomic
// row sum-of-squares; norm_gate2 elementwise; final GEMM fully async.
//
// R17->R18: XCD swizzle REVERTED (proj 44.5->71us). The default round-robin
// dispatch (XCD = bx%8) already gives optimal A-operand locality: each XCD
// touches only the 4 X row-slices with bx==i (mod 8) (~1MB/XCD L2); the
// chunked swizzle made every XCD stream all 8MB of X. T1 applies only when
// the default modular mapping scatters panel-sharers -- here it doesn't.
// This is the R16 (185.5us best-known) configuration restored verbatim.
// All R11 conflict-free layouts preserved (conflicts == 0 verified).

typedef short short8 __attribute__((ext_vector_type(8)));
typedef float f32x4 __attribute__((ext_vector_type(4)));

#define T_SEQ 2048
#define HIDN  1024
#define SCALE 0.08838834764831845f   // 128^-0.5
#define LDSP  136                    // padded LDS row stride (shorts)

// ---------------- bf16 bit helpers ----------------
__device__ __forceinline__ float blo(unsigned int u){
  union{unsigned int i; float f;} v; v.i = u << 16; return v.f;
}
__device__ __forceinline__ float bhi(unsigned int u){
  union{unsigned int i; float f;} v; v.i = u & 0xffff0000u; return v.f;
}
__device__ __forceinline__ float bu2f(unsigned short u){
  union{unsigned int i; float f;} v; v.i = ((unsigned int)u) << 16; return v.f;
}
__device__ __forceinline__ unsigned short f2bu(float f){
  union{float f; unsigned int i;} v; v.f = f;
  unsigned int x = v.i;
  x += 0x7fffu + ((x >> 16) & 1u);     // RNE
  return (unsigned short)(x >> 16);
}
__device__ __forceinline__ void async16(const void* g, void* l){
  __builtin_amdgcn_global_load_lds(
      (const __attribute__((address_space(1))) unsigned int*)g,
      (__attribute__((address_space(3))) unsigned int*)l, 16, 0, 0);
}

// ---------------- fused input cast + SumSq zeroing ------------------------
__global__ __launch_bounds__(256) void convert_all(
    const float* __restrict__ X,  const float* __restrict__ Wq,
    const float* __restrict__ Wk, const float* __restrict__ Wv,
    const float* __restrict__ Wg1,const float* __restrict__ Wg2,
    const float* __restrict__ gnw,const float* __restrict__ Wo,
    unsigned short* __restrict__ base, float* __restrict__ SumSq)
{
  int q = blockIdx.x * 256 + threadIdx.x;
  const float* src; unsigned short* dst; int rel = q;
  if (rel < 1048576)            { src = X;   dst = base;            }
  else if ((rel -= 1048576) < 262144) { src = Wq;  dst = base + 4194304; }
  else if ((rel -=  262144) < 262144) { src = Wk;  dst = base + 5242880; }
  else if ((rel -=  262144) < 262144) { src = Wv;  dst = base + 6291456; }
  else if ((rel -=  262144) < 262144) { src = Wo;  dst = base + 7340032; }
  else if ((rel -=  262144) <  32768) { src = Wg1; dst = base + 8388608; }
  else if ((rel -=   32768) <  32768) { src = Wg2; dst = base + 8519680; }
  else if ((rel -=   32768) <    256) { src = gnw; dst = base + 8650752; }
  else { rel -= 256;                              // zero SumSq (4096 floats)
    ((float4*)SumSq)[rel] = make_float4(0.f,0.f,0.f,0.f); return; }
  float4 v = ((const float4*)src)[rel];
  ushort4 o; o.x=f2bu(v.x); o.y=f2bu(v.y); o.z=f2bu(v.z); o.w=f2bu(v.w);
  ((ushort4*)dst)[rel] = o;
}

// ---------------- MFMA GEMM core: C(128x128)=A@B^T, BK=64 ----------------
// LDS tile [128 rows][8 chunks of 16B]; chunk cl of row r holds source
// chunk cl^(r&7) (involution; applied on the global source address so the
// global_load_lds destination stays linear). Frag reads use the same XOR:
// lanes 0-7 hit 8 distinct quad-bank groups -> conflict-free.
__device__ __forceinline__ void gemm_core(
    const unsigned short* __restrict__ A, const unsigned short* __restrict__ B,
    int K, int row0, int col0,
    unsigned short* sA, unsigned short* sB, f32x4 acc[4][4], int tid)
{
  const int lane = tid & 63;
  const int wm = (tid >> 6) & 1, wn = tid >> 7;
  const int wb = tid & 192;                // wave-uniform chunk base
  for (int k0 = 0; k0 < K; k0 += 64){
    __syncthreads();                       // prev iter's LDS reads done
#pragma unroll
    for (int r = 0; r < 4; ++r){
      int idx  = r*256 + tid;              // 1024 chunks of 16B per tile
      int mrow = idx >> 3;                 // row 0..127
      int kc   = ((idx & 7) ^ (mrow & 7)) * 8;   // pre-swizzled source col
      async16(A + (size_t)(row0 + mrow)*K + k0 + kc,
              sA + (size_t)(r*256 + wb)*8);
      async16(B + (size_t)(col0 + mrow)*K + k0 + kc,
              sB + (size_t)(r*256 + wb)*8);
    }
    __syncthreads();                       // drains vmcnt before barrier
#pragma unroll
    for (int h = 0; h < 2; ++h){
      short8 av[4], bv[4];
#pragma unroll
      for (int i=0;i<4;i++){
        int ra = wm*64 + i*16 + (lane&15);
        av[i] = *(const short8*)(sA + (size_t)ra*64
                                 + (((h*4 + (lane>>4)) ^ (ra & 7)) * 8));
      }
#pragma unroll
      for (int j=0;j<4;j++){
        int rb = wn*64 + j*16 + (lane&15);
        bv[j] = *(const short8*)(sB + (size_t)rb*64
                                 + (((h*4 + (lane>>4)) ^ (rb & 7)) * 8));
      }
#pragma unroll
      for (int i=0;i<4;i++)
#pragma unroll
        for (int j=0;j<4;j++)
          acc[i][j] = __builtin_amdgcn_mfma_f32_16x16x32_bf16(av[i], bv[j], acc[i][j], 0, 0, 0);
    }
  }
}

// bf16 epilogue via LDS. act: 0 none, 1 silu/swish, 2 exp.
__device__ __forceinline__ void epilogue_lds(
    f32x4 acc[4][4], int row0, int col0, int tid, int ldc, int act,
    unsigned short* __restrict__ Cb, unsigned short* sC)
{
  const int lane = tid & 63;
  const int wm = (tid >> 6) & 1, wn = tid >> 7;
#pragma unroll
  for (int p=0;p<4;p++){
    __syncthreads();
    if (wm == (p>>1)){
#pragma unroll
      for (int ii=0; ii<2; ii++){
        int i = (p&1)*2 + ii;
        int lr = i*16 + ((lane>>4)<<2) - (p&1)*32;   // local row in [0,32)
#pragma unroll
        for (int j=0;j<4;j++){
          int col = wn*64 + j*16 + (lane&15);
#pragma unroll
          for (int r=0;r<4;r++){
            float v = acc[i][j][r];
            if (act == 1) v = v / (1.f + __expf(-v));
            else if (act == 2) v = __expf(v);
            sC[(lr+r)*128 + col] = f2bu(v);
          }
        }
      }
    }
    __syncthreads();
#pragma unroll
    for (int c = tid; c < 512; c += 256){  // 32 rows x 256B
      int rr = c >> 4, off = (c & 15)*8;
      *(uint4*)&Cb[(size_t)(row0 + p*32 + rr)*ldc + col0 + off] =
          *(const uint4*)&sC[rr*128 + off];
    }
  }
}

// fp32 direct epilogue (64B full-line segments).
__device__ __forceinline__ void epilogue_f32(
    f32x4 acc[4][4], int row0, int col0, int tid, int ldc,
    float* __restrict__ Cf)
{
  const int lane = tid & 63;
  const int wm = (tid >> 6) & 1, wn = tid >> 7;
#pragma unroll
  for (int i=0;i<4;i++){
    int rbase = row0 + wm*64 + i*16 + ((lane>>4)<<2);
#pragma unroll
    for (int j=0;j<4;j++){
      int col = col0 + wn*64 + j*16 + (lane&15);
#pragma unroll
      for (int r=0;r<4;r++)
        Cf[(size_t)(rbase + r)*ldc + col] = acc[i][j][r];
    }
  }
}

// V^T epilogue: direct ushort4 stores, VT[(b*8+h)*128 + v][t:2048].
__device__ __forceinline__ void epilogue_vt(
    f32x4 acc[4][4], int row0, int col0, int tid,
    unsigned short* __restrict__ VT)
{
  const int lane = tid & 63, quad = lane >> 4, l15 = lane & 15;
  const int wm = (tid >> 6) & 1, wn = tid >> 7;
  size_t vtbase = ((size_t)(row0 >> 11)*8 + (col0 >> 7))*128;
  int trow0 = row0 & 2047;
#pragma unroll
  for (int i=0;i<4;i++){
    int t = trow0 + wm*64 + i*16 + quad*4;
#pragma unroll
    for (int j=0;j<4;j++){
      int v = wn*64 + j*16 + l15;
      ushort4 o;
      o.x = f2bu(acc[i][j][0]); o.y = f2bu(acc[i][j][1]);
      o.z = f2bu(acc[i][j][2]); o.w = f2bu(acc[i][j][3]);
      *(ushort4*)&VT[(vtbase + v)*2048 + t] = o;
    }
  }
}

// Fused QKV+G1 projection. grid (32, 25): y<8 Q(silu), <16 K->e (exp),
// <24 V->V^T, ==24 G1.  (Default dispatch: XCD = bx%8 -> X-slice locality.)
__global__ __launch_bounds__(256, 4) void proj_kernel(
    const unsigned short* __restrict__ X,
    const unsigned short* __restrict__ Wq, const unsigned short* __restrict__ Wk,
    const unsigned short* __restrict__ Wv, const unsigned short* __restrict__ Wg1,
    unsigned short* __restrict__ Qb, unsigned short* __restrict__ Eb,
    unsigned short* __restrict__ VT, unsigned short* __restrict__ G1b)
{
  __shared__ unsigned short sA[128*64], sB[128*64];
  int tid = threadIdx.x;
  int which = blockIdx.y >> 3;
  const unsigned short* Bp = (which==0)?Wq:(which==1)?Wk:(which==2)?Wv:Wg1;
  int row0 = blockIdx.x * 128;
  int col0 = (which==3) ? 0 : (blockIdx.y & 7) * 128;
  f32x4 acc[4][4] = {};
  gemm_core(X, Bp, HIDN, row0, col0, sA, sB, acc, tid);
  if      (which==0) epilogue_lds(acc,row0,col0,tid,HIDN,1,Qb, sA);
  else if (which==1) epilogue_lds(acc,row0,col0,tid,HIDN,2,Eb, sA);  // e=exp(k)
  else if (which==2) epilogue_vt (acc,row0,col0,tid,VT);
  else               epilogue_lds(acc,row0,col0,tid,128 ,0,G1b,sA);
}

// ---------------- 128x64-tile GEMM (2x blocks -> 2 blocks/CU) ------------
__device__ __forceinline__ void gemm_core64(
    const unsigned short* __restrict__ A, const unsigned short* __restrict__ B,
    int K, int row0, int col0,
    unsigned short* sA, unsigned short* sB, f32x4 acc[4][2], int tid)
{
  const int lane = tid & 63, quad = lane >> 4, l15 = lane & 15;
  const int wm = (tid >> 6) & 1, wn = tid >> 7;
  const int wb = tid & 192;
  for (int k0 = 0; k0 < K; k0 += 64){
    __syncthreads();
#pragma unroll
    for (int r = 0; r < 4; ++r){
      int idx  = r*256 + tid;
      int mrow = idx >> 3;
      int kc   = ((idx & 7) ^ (mrow & 7)) * 8;
      async16(A + (size_t)(row0 + mrow)*K + k0 + kc,
              sA + (size_t)(r*256 + wb)*8);
    }
#pragma unroll
    for (int r = 0; r < 2; ++r){
      int idx  = r*256 + tid;
      int brow = idx >> 3;                 // 0..63
      int kc   = ((idx & 7) ^ (brow & 7)) * 8;
      async16(B + (size_t)(col0 + brow)*K + k0 + kc,
              sB + (size_t)(r*256 + wb)*8);
    }
    __syncthreads();
#pragma unroll
    for (int h = 0; h < 2; ++h){
      short8 av[4], bv[2];
#pragma unroll
      for (int i=0;i<4;i++){
        int ra = wm*64 + i*16 + l15;
        av[i] = *(const short8*)(sA + (size_t)ra*64
                                 + (((h*4 + quad) ^ (ra & 7)) * 8));
      }
#pragma unroll
      for (int j=0;j<2;j++){
        int rb = wn*32 + j*16 + l15;
        bv[j] = *(const short8*)(sB + (size_t)rb*64
                                 + (((h*4 + quad) ^ (rb & 7)) * 8));
      }
#pragma unroll
      for (int i=0;i<4;i++)
#pragma unroll
        for (int j=0;j<2;j++)
          acc[i][j] = __builtin_amdgcn_mfma_f32_16x16x32_bf16(av[i], bv[j], acc[i][j], 0, 0, 0);
    }
  }
}

__global__ __launch_bounds__(256, 4) void gemm_bt64(
    const unsigned short* __restrict__ A, const unsigned short* __restrict__ B,
    int K, int ldc, int act, float* __restrict__ Cf,
    unsigned short* __restrict__ Cb)
{
  __shared__ unsigned short sA[128*64], sB[64*64];
  int tid = threadIdx.x;
  const int lane = tid & 63, quad = lane >> 4, l15 = lane & 15;
  const int wm = (tid >> 6) & 1, wn = tid >> 7;
  int row0 = blockIdx.x * 128, col0 = blockIdx.y * 64;
  f32x4 acc[4][2] = {};
  gemm_core64(A, B, K, row0, col0, sA, sB, acc, tid);
  if (Cb){
    unsigned short* sC = sA;               // 32 x 64 staging
#pragma unroll
    for (int p=0;p<4;p++){
      __syncthreads();
      if (wm == (p>>1)){
#pragma unroll
        for (int ii=0; ii<2; ii++){
          int i = (p&1)*2 + ii;
          int lr = i*16 + quad*4 - (p&1)*32;
#pragma unroll
          for (int j=0;j<2;j++){
            int col = wn*32 + j*16 + l15;
#pragma unroll
            for (int r=0;r<4;r++){
              float v = acc[i][j][r];
              if (act == 1) v = v / (1.f + __expf(-v));
              else if (act == 2) v = __expf(v);
              sC[(lr+r)*64 + col] = f2bu(v);
            }
          }
        }
      }
      __syncthreads();
      {
        int rr = tid >> 3, off = (tid & 7)*8;   // 32 rows x 128B
        *(uint4*)&Cb[(size_t)(row0 + p*32 + rr)*ldc + col0 + off] =
            *(const uint4*)&sC[rr*64 + off];
      }
    }
  } else {
#pragma unroll
    for (int i=0;i<4;i++){
      int rbase = row0 + wm*64 + i*16 + quad*4;
#pragma unroll
      for (int j=0;j<2;j++){
        int col = col0 + wn*32 + j*16 + l15;
#pragma unroll
        for (int r=0;r<4;r++)
          Cf[(size_t)(rbase + r)*ldc + col] = acc[i][j][r];
      }
    }
  }
}

// ---------------- pass 1 (MFMA): Esum[k], Ut[v][k] = sum_s V[s][v] e[s][k]
// k-SPLIT: grid 512 = (bh:4 | ch:4 | kh:1), 512 thr = 8 waves, ~51 KB LDS
// -> 2 independent blocks/CU. Each block: full V^T (async16, XOR-chunked),
// its own 64-col e-half transpose, Esum half, U k-half. No duplicated math.
__global__ __launch_bounds__(512, 4) void attn_pass1(
    const unsigned short* __restrict__ Eb, const unsigned short* __restrict__ VT,
    unsigned short* __restrict__ U, float* __restrict__ Esum)
{
  __shared__ unsigned short Vt[128*128];    // 32 KB, linear, XOR-chunked
  __shared__ unsigned short Et[64*LDSP];    // 17 KB (transposed e half)
  __shared__ float seg_part[8*64];
  int tid = threadIdx.x;
  const int lane = tid & 63, quad = lane >> 4, l15 = lane & 15;
  const int w = tid >> 6;                  // wave 0..7
  const int Rb = (w & 3)*32;               // v rows (2 i-tiles)
  const int Cbk = (w >> 2)*32;             // local k cols (2 j-tiles)
  int bx = blockIdx.x;
  int bh = bx >> 5, ch = (bx >> 1) & 15, kh = bx & 1;
  int b = bh >> 3, h = bh & 7;
  size_t rowbase = (size_t)(b*T_SEQ + ch*128)*HIDN + h*128 + kh*64;
  const unsigned short* VTb = VT + (size_t)bh*128*2048 + ch*128;

  // ---- stage V^T [v 128][s 128] via async16; source chunk-XOR swizzled ----
#pragma unroll
  for (int it=0; it<4; ++it){
    int slot = it*512 + tid;
    int vrow = slot >> 4, c = slot & 15;
    int cs = (c & 8) | ((c & 7) ^ (vrow & 7));
    async16(VTb + (size_t)vrow*2048 + cs*8,
            Vt + (size_t)(it*512 + (tid & 448))*8);
  }
  // ---- transpose-stage e half (rotated scalar stores) ----
#pragma unroll
  for (int i=0;i<2;i++){
    int u = tid + i*512; int t = u >> 3, kc = (u & 7)*8;
    int trot = (t + kc) & 127;
    unsigned short tmp[8];
    *(uint4*)tmp = *(const uint4*)&Eb[rowbase + (size_t)t*HIDN + kc];
#pragma unroll
    for (int j=0;j<8;j++) Et[(kc+j)*LDSP + trot] = tmp[j];
  }
  __syncthreads();

  { // Esum half: 64 k-rows, 8 segments of 16 t-cols
    int seg = tid >> 6, k = tid & 63;
    float s = 0.f;
    for (int c = seg*16; c < seg*16+16; ++c)
      s += bu2f(Et[k*LDSP + ((c + (k & 120)) & 127)]);
    seg_part[seg*64 + k] = s;
  }
  __syncthreads();
  if (tid < 64){
    float s = 0.f;
#pragma unroll
    for (int ss=0; ss<8; ++ss) s += seg_part[ss*64 + tid];
    Esum[(size_t)(bh*16 + ch)*128 + kh*64 + tid] = s;
  }

  // Ut-half = V^T @ Et^T (contraction over s); wave = 2x2 tiles of 16x16
  f32x4 acc[2][2] = {};
#pragma unroll
  for (int s0=0; s0<128; s0+=32){
    short8 av[2], bv[2];
#pragma unroll
    for (int i=0;i<2;i++){
      int ra = Rb + i*16 + l15;
      int ck = (s0>>3) + quad;
      int cx = (ck & 8) | ((ck & 7) ^ (ra & 7));
      av[i] = *(const short8*)(Vt + (size_t)ra*128 + cx*8);
    }
#pragma unroll
    for (int j=0;j<2;j++){
      int rb = Cbk + j*16 + l15;
      bv[j] = *(const short8*)(Et + rb*LDSP + ((s0 + quad*8 + (rb & 120)) & 127));
    }
#pragma unroll
    for (int i=0;i<2;i++)
#pragma unroll
      for (int j=0;j<2;j++)
        acc[i][j] = __builtin_amdgcn_mfma_f32_16x16x32_bf16(av[i], bv[j], acc[i][j], 0,0,0);
  }
  __syncthreads();                         // all Vt/Et reads done

  // stage C (bf16) into Vt region [v][64], coalesced copy-out
#pragma unroll
  for (int i=0;i<2;i++)
#pragma unroll
    for (int j=0;j<2;j++){
      int k = Cbk + j*16 + l15;
#pragma unroll
      for (int r=0;r<4;r++){
        int v = Rb + i*16 + quad*4 + r;
        Vt[v*64 + k] = f2bu(acc[i][j][r]);
      }
    }
  __syncthreads();
  unsigned short* Ub = U + (size_t)(bh*16 + ch)*16384;
#pragma unroll
  for (int i=0;i<2;i++){
    int u = tid + i*512; int v = u >> 3, kc8 = (u & 7)*8;
    *(uint4*)&Ub[v*128 + kh*64 + kc8] = *(const uint4*)&Vt[v*64 + kc8];
  }
}

// ---------------- pass 2: exclusive prefix over chunks (in place) ----------
// Depth-4 parallel scan: thread (pos,grp) loads its 4 chunks independently,
// local prefix, LDS exchange of group sums, write back. Grid 1024 (16 bh x
// 64 slices), 256 thr = 64 positions x 4 groups.
__global__ __launch_bounds__(256) void attn_pass2(
    unsigned short* __restrict__ U, float* __restrict__ Esum)
{
  __shared__ float4 gs[4][64];
  int tid = threadIdx.x;
  int bh = blockIdx.x >> 6, slice = blockIdx.x & 63;
  int pos = tid & 63, grp = tid >> 6;
  size_t P4 = ((size_t)slice*64 + pos)*4;          // short offset in plane
  ushort4 tv[4];
#pragma unroll
  for (int c=0;c<4;c++)                            // 4 INDEPENDENT loads
    tv[c] = *(const ushort4*)&U[(size_t)(bh*16 + grp*4 + c)*16384 + P4];
  float4 run = make_float4(0.f,0.f,0.f,0.f);
  float4 excl[4];
#pragma unroll
  for (int c=0;c<4;c++){
    excl[c] = run;
    run.x += bu2f(tv[c].x); run.y += bu2f(tv[c].y);
    run.z += bu2f(tv[c].z); run.w += bu2f(tv[c].w);
  }
  gs[grp][pos] = run;
  __syncthreads();
  float4 base = make_float4(0.f,0.f,0.f,0.f);
  for (int g=0; g<grp; ++g){
    float4 t = gs[g][pos];
    base.x += t.x; base.y += t.y; base.z += t.z; base.w += t.w;
  }
#pragma unroll
  for (int c=0;c<4;c++){
    ushort4 w4;
    w4.x = f2bu(base.x + excl[c].x); w4.y = f2bu(base.y + excl[c].y);
    w4.z = f2bu(base.z + excl[c].z); w4.w = f2bu(base.w + excl[c].w);
    *(ushort4*)&U[(size_t)(bh*16 + grp*4 + c)*16384 + P4] = w4;
  }
  if (slice < 2 && tid < 64){                      // Esum prefix (exact serial)
    int k = slice*64 + tid;
    float r = 0.f;
    for (int c=0;c<16;c++){
      float* q = &Esum[(size_t)(bh*16 + c)*128 + k];
      float t = *q; *q = r; r += t;
    }
  }
}

// ---------------- pass 3 (MFMA): o = qn@Cprev + causal(qn@e^T)@V + SumSq --
// 1024 threads = 16 waves, 2 blocks/CU (VGPR must stay <=64!).
// Ut read DIRECT from global (L2-resident, coalesced-per-row frags).
// bufA: Q->qn->P->Ostage ; bufB: e, then V^T (async16 overlay).
__global__ __launch_bounds__(1024, 2) void attn_pass3(
    const unsigned short* __restrict__ Eb, const unsigned short* __restrict__ Qb,
    const unsigned short* __restrict__ VT, const unsigned short* __restrict__ U,
    const float* __restrict__ Esum, unsigned short* __restrict__ Oatt,
    float* __restrict__ SumSq)
{
  __shared__ unsigned short bufA[128*LDSP];       // 34.8 KB
  __shared__ unsigned short bufB[128*LDSP];       // 34.8 KB (e, then V^T)
  __shared__ float seg_part[8*128];

  int tid = threadIdx.x;
  const int lane = tid & 63, quad = lane >> 4, l15 = lane & 15;
  const int w = tid >> 6;                  // wave 0..15
  const int Rb = (w & 3)*32;               // t rows (2 i-tiles)
  const int Cbn = (w >> 2)*32;             // s / v cols (2 j-tiles)
  int bh = blockIdx.x >> 4, ch = blockIdx.x & 15;
  int b = bh >> 3, h = bh & 7;
  size_t rowbase = (size_t)(b*T_SEQ + ch*128)*HIDN + h*128;
  const unsigned short* Ublk = U + (size_t)blockIdx.x*16384;
  const unsigned short* VTb = VT + (size_t)bh*128*2048 + ch*128;

  // ---- stage Q, e ----
#pragma unroll
  for (int i=0;i<2;i++){
    int u = tid + i*1024; int t = u >> 4, kc = (u & 15)*8;
    *(uint4*)&bufA[t*LDSP + kc] = *(const uint4*)&Qb[rowbase + (size_t)t*HIDN + kc];
    *(uint4*)&bufB[t*LDSP + kc] = *(const uint4*)&Eb[rowbase + (size_t)t*HIDN + kc];
  }
  __syncthreads();

  // ---- qn = q*SCALE/E_t ; 8-way segmented inclusive cumsum over t ----
  {
    int col = tid & 127, seg = tid >> 7;
    float psum = 0.f;
    for (int s = seg*16; s < seg*16+16; ++s) psum += bu2f(bufB[s*LDSP + col]);
    seg_part[seg*128 + col] = psum;
    __syncthreads();
    float run = Esum[(size_t)blockIdx.x*128 + col];
    for (int ss=0; ss<8; ++ss) if (ss < seg) run += seg_part[ss*128 + col];
    for (int s = seg*16; s < seg*16+16; ++s){
      run += bu2f(bufB[s*LDSP + col]);
      float q = bu2f(bufA[s*LDSP + col]);
      bufA[s*LDSP + col] = f2bu(q * SCALE * __builtin_amdgcn_rcpf(run));
    }
  }
  __syncthreads();

  // ---- inter: O = QN @ Ut^T (Ut direct from global) ; scores: P = QN@E^T --
  f32x4 accO[2][2] = {}, accP[2][2] = {};
#pragma unroll
  for (int k0=0; k0<128; k0+=32){
    short8 av[2], bv[2];
#pragma unroll
    for (int i=0;i<2;i++)
      av[i] = *(const short8*)(bufA + (Rb + i*16 + l15)*LDSP + k0 + quad*8);
#pragma unroll
    for (int j=0;j<2;j++)
      bv[j] = *(const short8*)(Ublk + (size_t)(Cbn + j*16 + l15)*128 + k0 + quad*8);
#pragma unroll
    for (int i=0;i<2;i++)
#pragma unroll
      for (int j=0;j<2;j++)
        accO[i][j] = __builtin_amdgcn_mfma_f32_16x16x32_bf16(av[i], bv[j], accO[i][j], 0,0,0);
#pragma unroll
    for (int j=0;j<2;j++)
      bv[j] = *(const short8*)(bufB + (Cbn + j*16 + l15)*LDSP + k0 + quad*8);
#pragma unroll
    for (int i=0;i<2;i++)
#pragma unroll
      for (int j=0;j<2;j++)
        accP[i][j] = __builtin_amdgcn_mfma_f32_16x16x32_bf16(av[i], bv[j], accP[i][j], 0,0,0);
  }
  __syncthreads();                        // all e reads done

  // ---- V^T -> bufB (async16, overlays e) ; masked P -> bufA [t][s] ----
#pragma unroll
  for (int it=0; it<2; ++it){
    int slot = it*1024 + tid;
    int vrow = slot >> 4, c = slot & 15;
    int cs = (c & 8) | ((c & 7) ^ (vrow & 7));
    async16(VTb + (size_t)vrow*2048 + cs*8,
            bufB + (size_t)(it*1024 + (tid & 960))*8);
  }
#pragma unroll
  for (int i=0;i<2;i++){
#pragma unroll
    for (int j=0;j<2;j++){
      int s = Cbn + j*16 + l15;
#pragma unroll
      for (int r=0;r<4;r++){
        int t = Rb + i*16 + quad*4 + r;
        bufA[t*LDSP + s] = f2bu(s <= t ? accP[i][j][r] : 0.f);
      }
    }
  }
  __syncthreads();                        // drains vmcnt (V^T) + lgkm (P)

  // ---- intra: O += P @ V^T (XOR-chunked bv reads) ----
#pragma unroll
  for (int k0=0; k0<128; k0+=32){
    short8 av[2], bv[2];
#pragma unroll
    for (int i=0;i<2;i++)
      av[i] = *(const short8*)(bufA + (Rb + i*16 + l15)*LDSP + k0 + quad*8);
#pragma unroll
    for (int j=0;j<2;j++){
      int rv = Cbn + j*16 + l15;
      int ck = (k0>>3) + quad;
      int cx = (ck & 8) | ((ck & 7) ^ (rv & 7));
      bv[j] = *(const short8*)(bufB + (size_t)rv*128 + cx*8);
    }
#pragma unroll
    for (int i=0;i<2;i++)
#pragma unroll
      for (int j=0;j<2;j++)
        accO[i][j] = __builtin_amdgcn_mfma_f32_16x16x32_bf16(av[i], bv[j], accO[i][j], 0,0,0);
  }
  __syncthreads();                        // all bufA (P) reads done

  // ---- O -> bufA (bf16) ----
#pragma unroll
  for (int i=0;i<2;i++){
#pragma unroll
    for (int j=0;j<2;j++){
      int vv = Cbn + j*16 + l15;
#pragma unroll
      for (int r=0;r<4;r++){
        int t = Rb + i*16 + quad*4 + r;
        bufA[t*LDSP + vv] = f2bu(accO[i][j][r]);
      }
    }
  }
  __syncthreads();

  // ---- per-row sum of squares (this head's 128 cols) ----
  {
    int seg = tid >> 7, row = tid & 127;
    float s = 0.f;
    for (int c = seg*16; c < seg*16+16; ++c){
      float x = bu2f(bufA[row*LDSP + c]); s += x*x;
    }
    seg_part[seg*128 + row] = s;
  }
  // ---- coalesced O write ----
#pragma unroll
  for (int i=0;i<2;i++){
    int u = tid + i*1024; int t = u >> 4, kc = (u & 15)*8;
    *(uint4*)&Oatt[rowbase + (size_t)t*HIDN + kc] = *(const uint4*)&bufA[t*LDSP + kc];
  }
  __syncthreads();
  if (tid < 128){
    float s = 0.f;
#pragma unroll
    for (int ss=0; ss<8; ++ss) s += seg_part[ss*128 + tid];
    atomicAdd(&SumSq[(size_t)b*T_SEQ + ch*128 + tid], s);
  }
}

// ---- norm_gate2: elementwise RMSNorm(SumSq)*gnw*swish-gate -> bf16 -------
// 2 rows/block, uint4 (8 bf16) per thread.
__global__ __launch_bounds__(256) void norm_gate2(
    const unsigned short* __restrict__ Oatt, const unsigned short* __restrict__ Gt,
    const unsigned short* __restrict__ gnw, const float* __restrict__ SumSq,
    unsigned short* __restrict__ Onorm)
{
  int tid = threadIdx.x;
  int row = blockIdx.x*2 + (tid >> 7);
  int col = (tid & 127)*8;
  float rstd = rsqrtf(SumSq[row] * (1.f/1024.f) + 1e-5f);
  uint4 o4 = *(const uint4*)&Oatt[(size_t)row*HIDN + col];
  uint4 g4 = *(const uint4*)&Gt  [(size_t)row*HIDN + col];
  uint4 w4 = *(const uint4*)&gnw[col];
  auto mul2 = [&](unsigned int o, unsigned int g, unsigned int wv)->unsigned int{
    float lo = blo(o) * rstd * blo(wv) * blo(g);
    float hi = bhi(o) * rstd * bhi(wv) * bhi(g);
    return (unsigned int)f2bu(lo) | ((unsigned int)f2bu(hi) << 16);
  };
  uint4 r4;
  r4.x = mul2(o4.x, g4.x, w4.x); r4.y = mul2(o4.y, g4.y, w4.y);
  r4.z = mul2(o4.z, g4.z, w4.z); r4.w = mul2(o4.w, g4.w, w4.w);
  *(uint4*)&Onorm[(size_t)row*HIDN + col] = r4;
}

// ---------------- launch ----------------
extern "C" void kernel_launch(void* const* d_in, const int* in_sizes, int n_in,
                              void* d_out, int out_size, void* d_ws, size_t ws_size,
                              hipStream_t stream) {
  unsigned short* wsS = (unsigned short*)d_ws;     // ~69 MiB used

  unsigned short* Xc   = wsS;              // 4,194,304
  unsigned short* Wqc  = wsS + 4194304;
  unsigned short* Wkc  = wsS + 5242880;
  unsigned short* Wvc  = wsS + 6291456;
  unsigned short* Woc  = wsS + 7340032;
  unsigned short* Wg1c = wsS + 8388608;
  unsigned short* Wg2c = wsS + 8519680;
  unsigned short* gnwc = wsS + 8650752;
  unsigned short* Qb   = wsS + 8651776;
  unsigned short* Eb   = wsS + 12846080;   // e = exp(k), bf16
  unsigned short* VTb  = wsS + 17040384;   // V^T: [(b*8+h)*128 + v][t:2048]
  unsigned short* G1b  = wsS + 21234688;
  unsigned short* Gt   = wsS + 21758976;
  unsigned short* Ub   = wsS + 25953280;
  unsigned short* Oattb= wsS + 30147584;
  float*          Esum = (float*)(wsS + 34341888);  // 32,768 floats
  float*          SumSq= (float*)(wsS + 34407424);  //  4,096 floats
  unsigned short* Onorm = Qb;              // Q dead after pass3

  convert_all<<<8453, 256, 0, stream>>>(
      (const float*)d_in[0], (const float*)d_in[1], (const float*)d_in[2],
      (const float*)d_in[3], (const float*)d_in[4], (const float*)d_in[5],
      (const float*)d_in[6], (const float*)d_in[7], wsS, SumSq);

  proj_kernel<<<dim3(32,25), 256, 0, stream>>>(Xc, Wqc, Wkc, Wvc, Wg1c, Qb, Eb, VTb, G1b);
  gemm_bt64 <<<dim3(32,16), 256, 0, stream>>>(G1b, Wg2c, 128, HIDN, 1, nullptr, Gt);
  attn_pass1<<<512, 512, 0, stream>>>(Eb, VTb, Ub, Esum);
  attn_pass2<<<1024, 256, 0, stream>>>(Ub, Esum);
  attn_pass3<<<256, 1024, 0, stream>>>(Eb, Qb, VTb, Ub, Esum, Oattb, SumSq);
  norm_gate2<<<2048, 256, 0, stream>>>(Oattb, Gt, gnwc, SumSq, Onorm);
  gemm_bt64 <<<dim3(32,16), 256, 0, stream>>>(Onorm, Woc, HIDN, 1024, 0,
                                              (float*)d_out, nullptr);
}